// Round 1
// baseline (617.264 us; speedup 1.0000x reference)
//
#include <hip/hip_runtime.h>
#include <hip/hip_bf16.h>

typedef unsigned short u16;
typedef unsigned int   u32;
typedef __attribute__((ext_vector_type(8))) short  short8;
typedef __attribute__((ext_vector_type(4))) short  short4v;
typedef __attribute__((ext_vector_type(4))) float  f32x4;

// ---------- helpers ----------
static __device__ __forceinline__ u16 f2bf(float f) {
  u32 u = __builtin_bit_cast(u32, f);
  u = (u + 0x7fffu + ((u >> 16) & 1u)) >> 16;
  return (u16)u;
}
static __device__ __forceinline__ float bf2f(u16 b) {
  return __builtin_bit_cast(float, (u32)b << 16);
}

#define MFMA_16x16x32(A,B,C) __builtin_amdgcn_mfma_f32_16x16x32_bf16((A),(B),(C),0,0,0)

static __device__ __forceinline__ void gload_lds16(const u16* g, u16* lds) {
  __builtin_amdgcn_global_load_lds((const __attribute__((address_space(1))) u32*)g,
                                   (__attribute__((address_space(3))) u32*)lds, 16, 0, 0);
}

static __device__ __forceinline__ float mishf(float x) {
  float sp = fmaxf(x, 0.f) + log1pf(__expf(-fabsf(x)));
  return x * tanhf(sp);
}

// ---------- cast fp32 -> bf16 (vectorized) ----------
__global__ __launch_bounds__(256) void cast_bf16_kernel(const float* __restrict__ x,
                                                        u16* __restrict__ o) {
  int i = (blockIdx.x * 256 + threadIdx.x) * 4;
  float4 v = *(const float4*)&x[i];
  short4v s;
  s[0] = (short)f2bf(v.x); s[1] = (short)f2bf(v.y);
  s[2] = (short)f2bf(v.z); s[3] = (short)f2bf(v.w);
  *(short4v*)&o[i] = s;
}

// ---------- transpose + cast: W[K][N] fp32 -> Out[N][K] bf16 ----------
__global__ __launch_bounds__(256) void transpose_cast_kernel(const float* __restrict__ W,
                                                             u16* __restrict__ Out,
                                                             int K, int N) {
  __shared__ float tile[32][33];
  const int k0 = blockIdx.y * 32, n0 = blockIdx.x * 32;
  const int tx = threadIdx.x & 31, ty = threadIdx.x >> 5;  // 32 x 8
  #pragma unroll
  for (int i = 0; i < 32; i += 8)
    tile[ty + i][tx] = W[(size_t)(k0 + ty + i) * N + n0 + tx];
  __syncthreads();
  #pragma unroll
  for (int i = 0; i < 32; i += 8)
    Out[(size_t)(n0 + ty + i) * K + k0 + tx] = f2bf(tile[tx][ty + i]);
}

// ---------- GEMM: C[M][N] = A[M][K](bf16) @ Bt[N][K](bf16)^T ----------
// EPI: 0 = store bf16, 1 = store fp32, 2 = +bias, mish, store bf16, 3 = +bias store fp32
template<int EPI>
__global__ __launch_bounds__(256, 2)
void gemm128(const u16* __restrict__ A, const u16* __restrict__ Bt,
             void* __restrict__ Cv, const float* __restrict__ bias,
             int M, int N, int K) {
  __shared__ __align__(16) u16 As[128 * 32];
  __shared__ __align__(16) u16 Bs[128 * 32];
  const int tid  = threadIdx.x;
  const int lane = tid & 63;
  const int wid  = tid >> 6;
  const int bm = blockIdx.y * 128;
  const int bn = blockIdx.x * 128;
  const int wr = (wid >> 1) * 64;
  const int wc = (wid & 1) * 64;

  f32x4 acc[4][4];
  #pragma unroll
  for (int i = 0; i < 4; i++)
    #pragma unroll
    for (int j = 0; j < 4; j++) acc[i][j] = (f32x4){0.f, 0.f, 0.f, 0.f};

  // staging geometry: each wave fills LDS rows [wid*16, wid*16+16) of each 64-row half
  const int srow = wid * 16 + (lane >> 2);
  const int scol = (lane & 3) * 8;
  const u16* Ag0 = A  + (size_t)(bm + srow) * K + scol;
  const u16* Ag1 = A  + (size_t)(bm + 64 + srow) * K + scol;
  const u16* Bg0 = Bt + (size_t)(bn + srow) * K + scol;
  const u16* Bg1 = Bt + (size_t)(bn + 64 + srow) * K + scol;
  u16* As0 = &As[wid * 512];
  u16* As1 = &As[2048 + wid * 512];
  u16* Bs0 = &Bs[wid * 512];
  u16* Bs1 = &Bs[2048 + wid * 512];

  const int fr = lane & 15;
  const int fk = (lane >> 4) * 8;

  for (int k0 = 0; k0 < K; k0 += 32) {
    gload_lds16(Ag0 + k0, As0);
    gload_lds16(Ag1 + k0, As1);
    gload_lds16(Bg0 + k0, Bs0);
    gload_lds16(Bg1 + k0, Bs1);
    __syncthreads();
    short8 af[4], bf[4];
    #pragma unroll
    for (int i = 0; i < 4; i++) af[i] = *(const short8*)&As[(wr + i * 16 + fr) * 32 + fk];
    #pragma unroll
    for (int j = 0; j < 4; j++) bf[j] = *(const short8*)&Bs[(wc + j * 16 + fr) * 32 + fk];
    #pragma unroll
    for (int i = 0; i < 4; i++)
      #pragma unroll
      for (int j = 0; j < 4; j++)
        acc[i][j] = MFMA_16x16x32(af[i], bf[j], acc[i][j]);
    __syncthreads();
  }

  // epilogue: D row = (lane>>4)*4 + r, col = lane&15   [measured m89 layout]
  const int r0 = (lane >> 4) * 4;
  #pragma unroll
  for (int i = 0; i < 4; i++) {
    const int row = bm + wr + i * 16 + r0;
    #pragma unroll
    for (int j = 0; j < 4; j++) {
      const int col = bn + wc + j * 16 + fr;
      float bv = 0.f;
      if (EPI >= 2) bv = bias[col];
      #pragma unroll
      for (int r = 0; r < 4; r++) {
        float v = acc[i][j][r] + bv;
        if (EPI == 2) v = mishf(v);
        if (EPI == 0 || EPI == 2)
          ((u16*)Cv)[(size_t)(row + r) * N + col] = f2bf(v);
        else
          ((float*)Cv)[(size_t)(row + r) * N + col] = v;
      }
    }
  }
}

// ---------- flash attention ----------
// qkv: [B*T][3072] bf16, cols = which*1024 + h*64 + d.  ctx out: [B*T][1024] bf16.
// grid: (32 q-tiles of 64 rows, 32 bh). block 256 = 4 waves; wave handles 16 q rows.
__global__ __launch_bounds__(256, 2)
void attn_kernel(const u16* __restrict__ qkv, u16* __restrict__ ctx) {
  const int bh = blockIdx.y;
  const int b = bh >> 4, h = bh & 15;
  const int qt = blockIdx.x;
  const int tid = threadIdx.x, lane = tid & 63, wid = tid >> 6;

  __shared__ __align__(16) u16 Ks[32 * 72];      // [kt][d], padded to 72
  __shared__ __align__(16) u16 Vt[64 * 40];      // [d][kt], padded to 40
  __shared__ __align__(16) u16 Ps[4][16 * 40];   // per-wave P tile, padded rows of 40

  const size_t base = (size_t)b * 2048 * 3072;
  const int fr  = lane & 15;
  const int fkb = lane >> 4;   // k-chunk: k = fkb*8 + i

  // Q fragments held in registers (A-frag: row = lane%16, k = (lane/16)*8+i)
  short8 qf[2];
  {
    const int qrow = qt * 64 + wid * 16 + fr;
    const u16* qp = qkv + base + (size_t)qrow * 3072 + h * 64 + fkb * 8;
    qf[0] = *(const short8*)qp;
    qf[1] = *(const short8*)(qp + 32);
  }

  float m_r[4], l_r[4];
  f32x4 o[4];
  #pragma unroll
  for (int r = 0; r < 4; r++) { m_r[r] = -1e30f; l_r[r] = 0.f; }
  #pragma unroll
  for (int d = 0; d < 4; d++) o[d] = (f32x4){0.f, 0.f, 0.f, 0.f};

  const int srow = tid >> 3;         // 0..31 (kv row within tile)
  const int sd   = (tid & 7) * 8;    // d offset

  for (int kt = 0; kt < 2048; kt += 32) {
    // stage K row-major (padded) and V transposed
    const u16* kp = qkv + base + (size_t)(kt + srow) * 3072 + 1024 + h * 64 + sd;
    short8 kv = *(const short8*)kp;
    short8 vv = *(const short8*)(kp + 1024);
    *(short8*)&Ks[srow * 72 + sd] = kv;
    #pragma unroll
    for (int i = 0; i < 8; i++) Vt[(sd + i) * 40 + srow] = (u16)vv[i];
    __syncthreads();

    // S = Q @ K^T (two 16x16 fragments covering kt..kt+31)
    f32x4 s[2];
    #pragma unroll
    for (int nb = 0; nb < 2; nb++) {
      short8 kf0 = *(const short8*)&Ks[(nb * 16 + fr) * 72 + fkb * 8];
      short8 kf1 = *(const short8*)&Ks[(nb * 16 + fr) * 72 + 32 + fkb * 8];
      f32x4 z = (f32x4){0.f, 0.f, 0.f, 0.f};
      z = MFMA_16x16x32(qf[0], kf0, z);
      z = MFMA_16x16x32(qf[1], kf1, z);
      s[nb] = z * 0.125f;  // 1/sqrt(64)
    }

    // online softmax (row = fkb*4 + r, cols across 16-lane group)
    #pragma unroll
    for (int r = 0; r < 4; r++) {
      float mx = fmaxf(s[0][r], s[1][r]);
      #pragma unroll
      for (int off = 1; off < 16; off <<= 1) mx = fmaxf(mx, __shfl_xor(mx, off, 64));
      float mnew = fmaxf(m_r[r], mx);
      float corr = __expf(m_r[r] - mnew);
      float p0 = __expf(s[0][r] - mnew);
      float p1 = __expf(s[1][r] - mnew);
      float ps = p0 + p1;
      #pragma unroll
      for (int off = 1; off < 16; off <<= 1) ps += __shfl_xor(ps, off, 64);
      l_r[r] = l_r[r] * corr + ps;
      m_r[r] = mnew;
      #pragma unroll
      for (int d = 0; d < 4; d++) o[d][r] *= corr;
      s[0][r] = p0; s[1][r] = p1;
    }

    // P -> per-wave LDS (row = fkb*4+r, col = nb*16+fr), then read back as A-frag
    #pragma unroll
    for (int nb = 0; nb < 2; nb++)
      #pragma unroll
      for (int r = 0; r < 4; r++)
        Ps[wid][(fkb * 4 + r) * 40 + nb * 16 + fr] = f2bf(s[nb][r]);
    short8 pf = *(const short8*)&Ps[wid][fr * 40 + fkb * 8];

    // O += P @ V  (B-frag from Vt: B[k][n] = V[kt][d], n = db*16+fr)
    #pragma unroll
    for (int db = 0; db < 4; db++) {
      short8 vf = *(const short8*)&Vt[(db * 16 + fr) * 40 + fkb * 8];
      o[db] = MFMA_16x16x32(pf, vf, o[db]);
    }
    __syncthreads();
  }

  // write ctx (bf16), row = qt*64 + wid*16 + fkb*4 + r, col = h*64 + db*16 + fr
  #pragma unroll
  for (int db = 0; db < 4; db++)
    #pragma unroll
    for (int r = 0; r < 4; r++) {
      float v = o[db][r] / l_r[r];
      int row = qt * 64 + wid * 16 + fkb * 4 + r;
      ctx[(size_t)(b * 2048 + row) * 1024 + h * 64 + db * 16 + fr] = f2bf(v);
    }
}

// ---------- residual + LayerNorm:  y = LN(2*res + add)*g + be ----------
__global__ __launch_bounds__(256, 4)
void ln_kernel(const float* __restrict__ res, const float* __restrict__ add,
               const float* __restrict__ g, const float* __restrict__ be,
               float* __restrict__ yout, u16* __restrict__ ybf) {
  const int row = blockIdx.x;
  const float* rp = res + (size_t)row * 1024;
  const float* ap = add + (size_t)row * 1024;
  const int c0 = threadIdx.x * 4;
  float4 rv = *(const float4*)&rp[c0];
  float4 av = *(const float4*)&ap[c0];
  float v[4] = {2.f * rv.x + av.x, 2.f * rv.y + av.y, 2.f * rv.z + av.z, 2.f * rv.w + av.w};
  float s = 0.f, sq = 0.f;
  #pragma unroll
  for (int i = 0; i < 4; i++) { s += v[i]; sq += v[i] * v[i]; }
  #pragma unroll
  for (int off = 32; off; off >>= 1) { s += __shfl_xor(s, off, 64); sq += __shfl_xor(sq, off, 64); }
  __shared__ float red[8];
  const int wid = threadIdx.x >> 6;
  if ((threadIdx.x & 63) == 0) { red[wid] = s; red[4 + wid] = sq; }
  __syncthreads();
  s  = red[0] + red[1] + red[2] + red[3];
  sq = red[4] + red[5] + red[6] + red[7];
  const float mu   = s * (1.f / 1024.f);
  const float var  = sq * (1.f / 1024.f) - mu * mu;
  const float rstd = rsqrtf(var + 1e-5f);
  #pragma unroll
  for (int i = 0; i < 4; i++) {
    const int c = c0 + i;
    float y = (v[i] - mu) * rstd * g[c] + be[c];
    yout[(size_t)row * 1024 + c] = y;
    if (ybf) ybf[(size_t)row * 1024 + c] = f2bf(y);
  }
}

// ---------- launch ----------
extern "C" void kernel_launch(void* const* d_in, const int* in_sizes, int n_in,
                              void* d_out, int out_size, void* d_ws, size_t ws_size,
                              hipStream_t stream) {
  const float* x   = (const float*)d_in[0];
  const float* Wq  = (const float*)d_in[1];
  const float* Wk  = (const float*)d_in[2];
  const float* Wv  = (const float*)d_in[3];
  const float* Wo  = (const float*)d_in[4];
  const float* W1  = (const float*)d_in[5];
  const float* b1  = (const float*)d_in[6];
  const float* W2  = (const float*)d_in[7];
  const float* b2  = (const float*)d_in[8];
  const float* g1  = (const float*)d_in[9];
  const float* be1 = (const float*)d_in[10];
  const float* g2  = (const float*)d_in[11];
  const float* be2 = (const float*)d_in[12];
  float* out = (float*)d_out;
  char* ws = (char*)d_ws;
  const size_t MB = 1024 * 1024;

  // lifetime-packed workspace (peak 80 MB):
  u16*   qkv   = (u16*)(ws + 0);        // [0,24) : dead after attn; y1/y1b written later
  float* y1    = (float*)(ws + 0);      // [0,16)
  u16*   y1b   = (u16*)(ws + 16 * MB);  // [16,24)
  u16*   hb    = (u16*)(ws + 24 * MB);  // [24,56) : written at FF1
  u16*   xb    = (u16*)(ws + 24 * MB);  // [24,32) sub-tenant, dead after qkv gemm
  u16*   WqkvT = (u16*)(ws + 32 * MB);  // [32,38) sub-tenant
  u16*   WoT   = (u16*)(ws + 38 * MB);  // [38,40) sub-tenant
  u16*   ctx   = (u16*)(ws + 40 * MB);  // [40,48) sub-tenant
  float* attnf = (float*)(ws + 56 * MB);// [56,72) : dead after ln1
  float* fff   = (float*)(ws + 56 * MB);// [56,72) : written at FF2
  u16*   W1T   = (u16*)(ws + 72 * MB);  // [72,80)
  u16*   W2T   = (u16*)(ws + 72 * MB);  // [72,80) : after W1T dead

  // t0: casts + QKV weight transposes
  cast_bf16_kernel<<<dim3(4096), dim3(256), 0, stream>>>(x, xb);
  transpose_cast_kernel<<<dim3(32, 32), dim3(256), 0, stream>>>(Wq, WqkvT, 1024, 1024);
  transpose_cast_kernel<<<dim3(32, 32), dim3(256), 0, stream>>>(Wk, WqkvT + 1024 * 1024, 1024, 1024);
  transpose_cast_kernel<<<dim3(32, 32), dim3(256), 0, stream>>>(Wv, WqkvT + 2 * 1024 * 1024, 1024, 1024);
  // t1: fused QKV projection
  gemm128<0><<<dim3(24, 32), dim3(256), 0, stream>>>(xb, WqkvT, qkv, nullptr, 4096, 3072, 1024);
  // t2: attention
  attn_kernel<<<dim3(32, 32), dim3(256), 0, stream>>>(qkv, ctx);
  // t3: output projection
  transpose_cast_kernel<<<dim3(32, 32), dim3(256), 0, stream>>>(Wo, WoT, 1024, 1024);
  gemm128<1><<<dim3(8, 32), dim3(256), 0, stream>>>(ctx, WoT, attnf, nullptr, 4096, 1024, 1024);
  // t4: LN1 (y1 = LN(2x + attn_out))
  ln_kernel<<<dim3(4096), dim3(256), 0, stream>>>(x, attnf, g1, be1, y1, y1b);
  // t5: FF1 with mish
  transpose_cast_kernel<<<dim3(128, 32), dim3(256), 0, stream>>>(W1, W1T, 1024, 4096);
  gemm128<2><<<dim3(32, 32), dim3(256), 0, stream>>>(y1b, W1T, hb, b1, 4096, 4096, 1024);
  // t6: FF2
  transpose_cast_kernel<<<dim3(32, 128), dim3(256), 0, stream>>>(W2, W2T, 4096, 1024);
  gemm128<3><<<dim3(8, 32), dim3(256), 0, stream>>>(hb, W2T, fff, b2, 4096, 1024, 4096);
  // t7: LN2 -> out
  ln_kernel<<<dim3(4096), dim3(256), 0, stream>>>(y1, fff, g2, be2, out, nullptr);
}

// Round 4
// 581.457 us; speedup vs baseline: 1.0616x; 1.0616x over previous
//
#include <hip/hip_runtime.h>
#include <hip/hip_bf16.h>

typedef unsigned short u16;
typedef unsigned int   u32;
typedef __attribute__((ext_vector_type(8))) short  short8;
typedef __attribute__((ext_vector_type(4))) short  short4v;
typedef __attribute__((ext_vector_type(4))) float  f32x4;

// ---------- helpers ----------
static __device__ __forceinline__ u16 f2bf(float f) {
  u32 u = __builtin_bit_cast(u32, f);
  u = (u + 0x7fffu + ((u >> 16) & 1u)) >> 16;
  return (u16)u;
}

#define MFMA_16x16x32(A,B,C) __builtin_amdgcn_mfma_f32_16x16x32_bf16((A),(B),(C),0,0,0)

static __device__ __forceinline__ void gload_lds16(const u16* g, u16* lds) {
  __builtin_amdgcn_global_load_lds((const __attribute__((address_space(1))) u32*)g,
                                   (__attribute__((address_space(3))) u32*)lds, 16, 0, 0);
}

static __device__ __forceinline__ float mishf(float x) {
  float sp = fmaxf(x, 0.f) + log1pf(__expf(-fabsf(x)));
  return x * tanhf(sp);
}

// ---------- cast fp32 -> bf16 (vectorized) ----------
__global__ __launch_bounds__(256) void cast_bf16_kernel(const float* __restrict__ x,
                                                        u16* __restrict__ o) {
  int i = (blockIdx.x * 256 + threadIdx.x) * 4;
  float4 v = *(const float4*)&x[i];
  short4v s;
  s[0] = (short)f2bf(v.x); s[1] = (short)f2bf(v.y);
  s[2] = (short)f2bf(v.z); s[3] = (short)f2bf(v.w);
  *(short4v*)&o[i] = s;
}

// ---------- transpose + cast: W[K][N] fp32 -> Out[N][K] bf16 ----------
__global__ __launch_bounds__(256) void transpose_cast_kernel(const float* __restrict__ W,
                                                             u16* __restrict__ Out,
                                                             int K, int N) {
  __shared__ float tile[32][33];
  const int k0 = blockIdx.y * 32, n0 = blockIdx.x * 32;
  const int tx = threadIdx.x & 31, ty = threadIdx.x >> 5;  // 32 x 8
  #pragma unroll
  for (int i = 0; i < 32; i += 8)
    tile[ty + i][tx] = W[(size_t)(k0 + ty + i) * N + n0 + tx];
  __syncthreads();
  #pragma unroll
  for (int i = 0; i < 32; i += 8)
    Out[(size_t)(n0 + ty + i) * K + k0 + tx] = f2bf(tile[tx][ty + i]);
}

// ---------- GEMM: C[M][N] = A[M][K](bf16) @ Bt[N][K](bf16)^T ----------
// EPI: 0 = store bf16, 1 = store fp32, 2 = +bias, mish, store bf16, 3 = +bias store fp32
template<int EPI>
__global__ __launch_bounds__(256, 2)
void gemm128(const u16* __restrict__ A, const u16* __restrict__ Bt,
             void* __restrict__ Cv, const float* __restrict__ bias,
             int M, int N, int K) {
  __shared__ __align__(16) u16 As[128 * 32];
  __shared__ __align__(16) u16 Bs[128 * 32];
  const int tid  = threadIdx.x;
  const int lane = tid & 63;
  const int wid  = tid >> 6;

  // XCD-aware swizzle (bijective: all grids here have nwg % 8 == 0)
  const u32 nwg = gridDim.x * gridDim.y;
  const u32 id  = blockIdx.y * gridDim.x + blockIdx.x;
  const u32 cpx = nwg >> 3;
  const u32 swz = (id & 7) * cpx + (id >> 3);
  const int bm = (swz / gridDim.x) * 128;
  const int bn = (swz % gridDim.x) * 128;

  const int wr = (wid >> 1) * 64;
  const int wc = (wid & 1) * 64;

  f32x4 acc[4][4];
  #pragma unroll
  for (int i = 0; i < 4; i++)
    #pragma unroll
    for (int j = 0; j < 4; j++) acc[i][j] = (f32x4){0.f, 0.f, 0.f, 0.f};

  const int srow = wid * 16 + (lane >> 2);
  const int scol = (lane & 3) * 8;
  const u16* Ag0 = A  + (size_t)(bm + srow) * K + scol;
  const u16* Ag1 = A  + (size_t)(bm + 64 + srow) * K + scol;
  const u16* Bg0 = Bt + (size_t)(bn + srow) * K + scol;
  const u16* Bg1 = Bt + (size_t)(bn + 64 + srow) * K + scol;
  u16* As0 = &As[wid * 512];
  u16* As1 = &As[2048 + wid * 512];
  u16* Bs0 = &Bs[wid * 512];
  u16* Bs1 = &Bs[2048 + wid * 512];

  const int fr = lane & 15;
  const int fk = (lane >> 4) * 8;

  for (int k0 = 0; k0 < K; k0 += 32) {
    gload_lds16(Ag0 + k0, As0);
    gload_lds16(Ag1 + k0, As1);
    gload_lds16(Bg0 + k0, Bs0);
    gload_lds16(Bg1 + k0, Bs1);
    __syncthreads();
    short8 af[4], bf[4];
    #pragma unroll
    for (int i = 0; i < 4; i++) af[i] = *(const short8*)&As[(wr + i * 16 + fr) * 32 + fk];
    #pragma unroll
    for (int j = 0; j < 4; j++) bf[j] = *(const short8*)&Bs[(wc + j * 16 + fr) * 32 + fk];
    #pragma unroll
    for (int i = 0; i < 4; i++)
      #pragma unroll
      for (int j = 0; j < 4; j++)
        acc[i][j] = MFMA_16x16x32(af[i], bf[j], acc[i][j]);
    __syncthreads();
  }

  const int r0 = (lane >> 4) * 4;
  #pragma unroll
  for (int i = 0; i < 4; i++) {
    const int row = bm + wr + i * 16 + r0;
    #pragma unroll
    for (int j = 0; j < 4; j++) {
      const int col = bn + wc + j * 16 + fr;
      float bv = 0.f;
      if (EPI >= 2) bv = bias[col];
      #pragma unroll
      for (int r = 0; r < 4; r++) {
        float v = acc[i][j][r] + bv;
        if (EPI == 2) v = mishf(v);
        if (EPI == 0 || EPI == 2)
          ((u16*)Cv)[(size_t)(row + r) * N + col] = f2bf(v);
        else
          ((float*)Cv)[(size_t)(row + r) * N + col] = v;
      }
    }
  }
}

// ---------- flash attention (round-1 structure; Vt columns rotated to kill bank conflicts) ----------
// qkv: [B*T][3072] bf16, cols = which*1024 + h*64 + d.  ctx out: [B*T][1024] bf16.
// grid: (32 q-tiles of 64 rows, 32 bh). block 256 = 4 waves; wave handles 16 q rows.
__global__ __launch_bounds__(256, 2)
void attn_kernel(const u16* __restrict__ qkv, u16* __restrict__ ctx) {
  const int bh = blockIdx.y;
  const int b = bh >> 4, h = bh & 15;
  const int qt = blockIdx.x;
  const int tid = threadIdx.x, lane = tid & 63, wid = tid >> 6;

  __shared__ __align__(16) u16 Ks[32 * 72];      // [kt][d], padded to 72
  __shared__ __align__(16) u16 Vt[64 * 40];      // [d][kt-rotated], pad 40
  __shared__ __align__(16) u16 Ps[4][16 * 40];   // per-wave P tile, padded rows of 40

  const size_t base = (size_t)b * 2048 * 3072;
  const int fr  = lane & 15;
  const int fkb = lane >> 4;   // k-chunk: k = fkb*8 + i

  // Q fragments held in registers (A-frag: row = lane%16, k = (lane/16)*8+i)
  short8 qf[2];
  {
    const int qrow = qt * 64 + wid * 16 + fr;
    const u16* qp = qkv + base + (size_t)qrow * 3072 + h * 64 + fkb * 8;
    qf[0] = *(const short8*)qp;
    qf[1] = *(const short8*)(qp + 32);
  }

  float m_r[4], l_r[4];
  f32x4 o[4];
  #pragma unroll
  for (int r = 0; r < 4; r++) { m_r[r] = -1e30f; l_r[r] = 0.f; }
  #pragma unroll
  for (int d = 0; d < 4; d++) o[d] = (f32x4){0.f, 0.f, 0.f, 0.f};

  const int srow = tid >> 3;         // 0..31 (kv row within tile)
  const int sd   = (tid & 7) * 8;    // d offset

  for (int kt = 0; kt < 2048; kt += 32) {
    // stage K row-major (padded) and V transposed (column rotated by 8*(d>>3) mod 32)
    const u16* kp = qkv + base + (size_t)(kt + srow) * 3072 + 1024 + h * 64 + sd;
    short8 kv = *(const short8*)kp;
    short8 vv = *(const short8*)(kp + 1024);
    *(short8*)&Ks[srow * 72 + sd] = kv;
    const int vcol = (srow + sd) & 31;   // 8*(d>>3) == sd for d in [sd, sd+8)
    #pragma unroll
    for (int i = 0; i < 8; i++) Vt[(sd + i) * 40 + vcol] = (u16)vv[i];
    __syncthreads();

    // S = Q @ K^T (two 16x16 fragments covering kt..kt+31)
    f32x4 s[2];
    #pragma unroll
    for (int nb = 0; nb < 2; nb++) {
      short8 kf0 = *(const short8*)&Ks[(nb * 16 + fr) * 72 + fkb * 8];
      short8 kf1 = *(const short8*)&Ks[(nb * 16 + fr) * 72 + 32 + fkb * 8];
      f32x4 z = (f32x4){0.f, 0.f, 0.f, 0.f};
      z = MFMA_16x16x32(qf[0], kf0, z);
      z = MFMA_16x16x32(qf[1], kf1, z);
      s[nb] = z * 0.125f;  // 1/sqrt(64)
    }

    // online softmax (row = fkb*4 + r, cols across 16-lane group)
    #pragma unroll
    for (int r = 0; r < 4; r++) {
      float mx = fmaxf(s[0][r], s[1][r]);
      #pragma unroll
      for (int off = 1; off < 16; off <<= 1) mx = fmaxf(mx, __shfl_xor(mx, off, 64));
      float mnew = fmaxf(m_r[r], mx);
      float corr = __expf(m_r[r] - mnew);
      float p0 = __expf(s[0][r] - mnew);
      float p1 = __expf(s[1][r] - mnew);
      float ps = p0 + p1;
      #pragma unroll
      for (int off = 1; off < 16; off <<= 1) ps += __shfl_xor(ps, off, 64);
      l_r[r] = l_r[r] * corr + ps;
      m_r[r] = mnew;
      #pragma unroll
      for (int d = 0; d < 4; d++) o[d][r] *= corr;
      s[0][r] = p0; s[1][r] = p1;
    }

    // P -> per-wave LDS (row = fkb*4+r, col = nb*16+fr), then read back as A-frag
    #pragma unroll
    for (int nb = 0; nb < 2; nb++)
      #pragma unroll
      for (int r = 0; r < 4; r++)
        Ps[wid][(fkb * 4 + r) * 40 + nb * 16 + fr] = f2bf(s[nb][r]);
    short8 pf = *(const short8*)&Ps[wid][fr * 40 + fkb * 8];

    // O += P @ V  (B-frag from Vt: B[k][n] = V[kt][d], n = db*16+fr; rotated column start)
    #pragma unroll
    for (int db = 0; db < 4; db++) {
      short8 vf = *(const short8*)&Vt[(db * 16 + fr) * 40 + 8 * ((fkb + 2 * db + (fr >> 3)) & 3)];
      o[db] = MFMA_16x16x32(pf, vf, o[db]);
    }
    __syncthreads();
  }

  // write ctx (bf16), row = qt*64 + wid*16 + fkb*4 + r, col = h*64 + db*16 + fr
  #pragma unroll
  for (int db = 0; db < 4; db++)
    #pragma unroll
    for (int r = 0; r < 4; r++) {
      float v = o[db][r] / l_r[r];
      int row = qt * 64 + wid * 16 + fkb * 4 + r;
      ctx[(size_t)(b * 2048 + row) * 1024 + h * 64 + db * 16 + fr] = f2bf(v);
    }
}

// ---------- residual + LayerNorm:  y = LN(2*res + add)*g + be ----------
__global__ __launch_bounds__(256, 4)
void ln_kernel(const float* __restrict__ res, const float* __restrict__ add,
               const float* __restrict__ g, const float* __restrict__ be,
               float* __restrict__ yout, u16* __restrict__ ybf) {
  const int row = blockIdx.x;
  const float* rp = res + (size_t)row * 1024;
  const float* ap = add + (size_t)row * 1024;
  const int c0 = threadIdx.x * 4;
  float4 rv = *(const float4*)&rp[c0];
  float4 av = *(const float4*)&ap[c0];
  float v[4] = {2.f * rv.x + av.x, 2.f * rv.y + av.y, 2.f * rv.z + av.z, 2.f * rv.w + av.w};
  float s = 0.f, sq = 0.f;
  #pragma unroll
  for (int i = 0; i < 4; i++) { s += v[i]; sq += v[i] * v[i]; }
  #pragma unroll
  for (int off = 32; off; off >>= 1) { s += __shfl_xor(s, off, 64); sq += __shfl_xor(sq, off, 64); }
  __shared__ float red[8];
  const int wid = threadIdx.x >> 6;
  if ((threadIdx.x & 63) == 0) { red[wid] = s; red[4 + wid] = sq; }
  __syncthreads();
  s  = red[0] + red[1] + red[2] + red[3];
  sq = red[4] + red[5] + red[6] + red[7];
  const float mu   = s * (1.f / 1024.f);
  const float var  = sq * (1.f / 1024.f) - mu * mu;
  const float rstd = rsqrtf(var + 1e-5f);
  #pragma unroll
  for (int i = 0; i < 4; i++) {
    const int c = c0 + i;
    float y = (v[i] - mu) * rstd * g[c] + be[c];
    yout[(size_t)row * 1024 + c] = y;
    if (ybf) ybf[(size_t)row * 1024 + c] = f2bf(y);
  }
}

// ---------- launch ----------
extern "C" void kernel_launch(void* const* d_in, const int* in_sizes, int n_in,
                              void* d_out, int out_size, void* d_ws, size_t ws_size,
                              hipStream_t stream) {
  const float* x   = (const float*)d_in[0];
  const float* Wq  = (const float*)d_in[1];
  const float* Wk  = (const float*)d_in[2];
  const float* Wv  = (const float*)d_in[3];
  const float* Wo  = (const float*)d_in[4];
  const float* W1  = (const float*)d_in[5];
  const float* b1  = (const float*)d_in[6];
  const float* W2  = (const float*)d_in[7];
  const float* b2  = (const float*)d_in[8];
  const float* g1  = (const float*)d_in[9];
  const float* be1 = (const float*)d_in[10];
  const float* g2  = (const float*)d_in[11];
  const float* be2 = (const float*)d_in[12];
  float* out = (float*)d_out;
  char* ws = (char*)d_ws;
  const size_t MB = 1024 * 1024;

  u16*   qkv   = (u16*)(ws + 0);
  float* y1    = (float*)(ws + 0);
  u16*   y1b   = (u16*)(ws + 16 * MB);
  u16*   hb    = (u16*)(ws + 24 * MB);
  u16*   xb    = (u16*)(ws + 24 * MB);
  u16*   WqkvT = (u16*)(ws + 32 * MB);
  u16*   WoT   = (u16*)(ws + 38 * MB);
  u16*   ctx   = (u16*)(ws + 40 * MB);
  float* attnf = (float*)(ws + 56 * MB);
  float* fff   = (float*)(ws + 56 * MB);
  u16*   W1T   = (u16*)(ws + 72 * MB);
  u16*   W2T   = (u16*)(ws + 72 * MB);

  cast_bf16_kernel<<<dim3(4096), dim3(256), 0, stream>>>(x, xb);
  transpose_cast_kernel<<<dim3(32, 32), dim3(256), 0, stream>>>(Wq, WqkvT, 1024, 1024);
  transpose_cast_kernel<<<dim3(32, 32), dim3(256), 0, stream>>>(Wk, WqkvT + 1024 * 1024, 1024, 1024);
  transpose_cast_kernel<<<dim3(32, 32), dim3(256), 0, stream>>>(Wv, WqkvT + 2 * 1024 * 1024, 1024, 1024);
  gemm128<0><<<dim3(24, 32), dim3(256), 0, stream>>>(xb, WqkvT, qkv, nullptr, 4096, 3072, 1024);
  attn_kernel<<<dim3(32, 32), dim3(256), 0, stream>>>(qkv, ctx);
  transpose_cast_kernel<<<dim3(32, 32), dim3(256), 0, stream>>>(Wo, WoT, 1024, 1024);
  gemm128<1><<<dim3(8, 32), dim3(256), 0, stream>>>(ctx, WoT, attnf, nullptr, 4096, 1024, 1024);
  ln_kernel<<<dim3(4096), dim3(256), 0, stream>>>(x, attnf, g1, be1, y1, y1b);
  transpose_cast_kernel<<<dim3(128, 32), dim3(256), 0, stream>>>(W1, W1T, 1024, 4096);
  gemm128<2><<<dim3(32, 32), dim3(256), 0, stream>>>(y1b, W1T, hb, b1, 4096, 4096, 1024);
  transpose_cast_kernel<<<dim3(32, 128), dim3(256), 0, stream>>>(W2, W2T, 4096, 1024);
  gemm128<3><<<dim3(8, 32), dim3(256), 0, stream>>>(hb, W2T, fff, b2, 4096, 1024, 4096);
  ln_kernel<<<dim3(4096), dim3(256), 0, stream>>>(y1, fff, g2, be2, out, nullptr);
}

// Round 5
// 510.031 us; speedup vs baseline: 1.2102x; 1.1400x over previous
//
#include <hip/hip_runtime.h>
#include <hip/hip_bf16.h>

typedef unsigned short u16;
typedef unsigned int   u32;
typedef __attribute__((ext_vector_type(8))) short  short8;
typedef __attribute__((ext_vector_type(4))) short  short4v;
typedef __attribute__((ext_vector_type(4))) float  f32x4;

// ---------- helpers ----------
static __device__ __forceinline__ u16 f2bf(float f) {
  u32 u = __builtin_bit_cast(u32, f);
  u = (u + 0x7fffu + ((u >> 16) & 1u)) >> 16;
  return (u16)u;
}

#define MFMA_16x16x32(A,B,C) __builtin_amdgcn_mfma_f32_16x16x32_bf16((A),(B),(C),0,0,0)

static __device__ __forceinline__ void gload_lds16(const u16* g, u16* lds) {
  __builtin_amdgcn_global_load_lds((const __attribute__((address_space(1))) u32*)g,
                                   (__attribute__((address_space(3))) u32*)lds, 16, 0, 0);
}

static __device__ __forceinline__ float mishf(float x) {
  float sp = fmaxf(x, 0.f) + log1pf(__expf(-fabsf(x)));
  return x * tanhf(sp);
}

// ---------- cast fp32 -> bf16 (vectorized) ----------
__global__ __launch_bounds__(256) void cast_bf16_kernel(const float* __restrict__ x,
                                                        u16* __restrict__ o) {
  int i = (blockIdx.x * 256 + threadIdx.x) * 4;
  float4 v = *(const float4*)&x[i];
  short4v s;
  s[0] = (short)f2bf(v.x); s[1] = (short)f2bf(v.y);
  s[2] = (short)f2bf(v.z); s[3] = (short)f2bf(v.w);
  *(short4v*)&o[i] = s;
}

// ---------- transpose + cast: W[K][N] fp32 -> Out[N][K] bf16 ----------
__global__ __launch_bounds__(256) void transpose_cast_kernel(const float* __restrict__ W,
                                                             u16* __restrict__ Out,
                                                             int K, int N) {
  __shared__ float tile[32][33];
  const int k0 = blockIdx.y * 32, n0 = blockIdx.x * 32;
  const int tx = threadIdx.x & 31, ty = threadIdx.x >> 5;  // 32 x 8
  #pragma unroll
  for (int i = 0; i < 32; i += 8)
    tile[ty + i][tx] = W[(size_t)(k0 + ty + i) * N + n0 + tx];
  __syncthreads();
  #pragma unroll
  for (int i = 0; i < 32; i += 8)
    Out[(size_t)(n0 + ty + i) * K + k0 + tx] = f2bf(tile[tx][ty + i]);
}

// ---------- GEMM: C[M][N] = A[M][K](bf16) @ Bt[N][K](bf16)^T ----------
// EPI: 0 = store bf16, 1 = store fp32, 2 = +bias, mish, store bf16, 3 = +bias store fp32
template<int EPI>
__global__ __launch_bounds__(256, 2)
void gemm128(const u16* __restrict__ A, const u16* __restrict__ Bt,
             void* __restrict__ Cv, const float* __restrict__ bias,
             int M, int N, int K) {
  __shared__ __align__(16) u16 As[128 * 32];
  __shared__ __align__(16) u16 Bs[128 * 32];
  const int tid  = threadIdx.x;
  const int lane = tid & 63;
  const int wid  = tid >> 6;

  // XCD-aware swizzle (bijective: all grids here have nwg % 8 == 0)
  const u32 nwg = gridDim.x * gridDim.y;
  const u32 id  = blockIdx.y * gridDim.x + blockIdx.x;
  const u32 cpx = nwg >> 3;
  const u32 swz = (id & 7) * cpx + (id >> 3);
  const int bm = (swz / gridDim.x) * 128;
  const int bn = (swz % gridDim.x) * 128;

  const int wr = (wid >> 1) * 64;
  const int wc = (wid & 1) * 64;

  f32x4 acc[4][4];
  #pragma unroll
  for (int i = 0; i < 4; i++)
    #pragma unroll
    for (int j = 0; j < 4; j++) acc[i][j] = (f32x4){0.f, 0.f, 0.f, 0.f};

  const int srow = wid * 16 + (lane >> 2);
  const int scol = (lane & 3) * 8;
  const u16* Ag0 = A  + (size_t)(bm + srow) * K + scol;
  const u16* Ag1 = A  + (size_t)(bm + 64 + srow) * K + scol;
  const u16* Bg0 = Bt + (size_t)(bn + srow) * K + scol;
  const u16* Bg1 = Bt + (size_t)(bn + 64 + srow) * K + scol;
  u16* As0 = &As[wid * 512];
  u16* As1 = &As[2048 + wid * 512];
  u16* Bs0 = &Bs[wid * 512];
  u16* Bs1 = &Bs[2048 + wid * 512];

  const int fr = lane & 15;
  const int fk = (lane >> 4) * 8;

  for (int k0 = 0; k0 < K; k0 += 32) {
    gload_lds16(Ag0 + k0, As0);
    gload_lds16(Ag1 + k0, As1);
    gload_lds16(Bg0 + k0, Bs0);
    gload_lds16(Bg1 + k0, Bs1);
    __syncthreads();
    short8 af[4], bf[4];
    #pragma unroll
    for (int i = 0; i < 4; i++) af[i] = *(const short8*)&As[(wr + i * 16 + fr) * 32 + fk];
    #pragma unroll
    for (int j = 0; j < 4; j++) bf[j] = *(const short8*)&Bs[(wc + j * 16 + fr) * 32 + fk];
    #pragma unroll
    for (int i = 0; i < 4; i++)
      #pragma unroll
      for (int j = 0; j < 4; j++)
        acc[i][j] = MFMA_16x16x32(af[i], bf[j], acc[i][j]);
    __syncthreads();
  }

  const int r0 = (lane >> 4) * 4;
  #pragma unroll
  for (int i = 0; i < 4; i++) {
    const int row = bm + wr + i * 16 + r0;
    #pragma unroll
    for (int j = 0; j < 4; j++) {
      const int col = bn + wc + j * 16 + fr;
      float bv = 0.f;
      if (EPI >= 2) bv = bias[col];
      #pragma unroll
      for (int r = 0; r < 4; r++) {
        float v = acc[i][j][r] + bv;
        if (EPI == 2) v = mishf(v);
        if (EPI == 0 || EPI == 2)
          ((u16*)Cv)[(size_t)(row + r) * N + col] = f2bf(v);
        else
          ((float*)Cv)[(size_t)(row + r) * N + col] = v;
      }
    }
  }
}

// ---------- flash attention (swapped QK^T softmax; rotated-Vt staging from round 4) ----------
// qkv: [B*T][3072] bf16, cols = which*1024 + h*64 + d.  ctx out: [B*T][1024] bf16.
// grid: (32 q-tiles of 64 rows, 32 bh). block 256 = 4 waves; wave handles 16 q rows.
__global__ __launch_bounds__(256, 2)
void attn_kernel(const u16* __restrict__ qkv, u16* __restrict__ ctx) {
  const int bh = blockIdx.y;
  const int b = bh >> 4, h = bh & 15;
  const int qt = blockIdx.x;
  const int tid = threadIdx.x, lane = tid & 63, wid = tid >> 6;

  __shared__ __align__(16) u16 Ks[32 * 72];      // [kt][d], padded to 72
  __shared__ __align__(16) u16 Vt[64 * 40];      // [d][kt-rotated], pad 40
  __shared__ __align__(16) u16 Ps[4][16 * 40];   // per-wave P tile [q][kv], rows of 40

  const size_t base = (size_t)b * 2048 * 3072;
  const int fr = lane & 15;
  const int g  = lane >> 4;   // 16-lane group

  // Q fragment: row/col = q = fr, k = d = g*8+i.  Serves as B-frag of swapped QK^T
  // (B: col=lane&15=q, k=(lane>>4)*8+i=d) — identical registers to the A-frag use.
  short8 qf[2];
  {
    const int qrow = qt * 64 + wid * 16 + fr;
    const u16* qp = qkv + base + (size_t)qrow * 3072 + h * 64 + g * 8;
    qf[0] = *(const short8*)qp;
    qf[1] = *(const short8*)(qp + 32);
  }

  float m_l = -1e30f, l_l = 0.f;   // running stats for q-row = fr
  f32x4 o[4];
  #pragma unroll
  for (int d = 0; d < 4; d++) o[d] = (f32x4){0.f, 0.f, 0.f, 0.f};

  const int srow = tid >> 3;         // 0..31 (kv row within tile)
  const int sd   = (tid & 7) * 8;    // d offset

  for (int kt = 0; kt < 2048; kt += 32) {
    // stage K row-major (padded) and V transposed (column rotated by sd mod 32)
    const u16* kp = qkv + base + (size_t)(kt + srow) * 3072 + 1024 + h * 64 + sd;
    short8 kv = *(const short8*)kp;
    short8 vv = *(const short8*)(kp + 1024);
    *(short8*)&Ks[srow * 72 + sd] = kv;
    const int vcol = (srow + sd) & 31;
    #pragma unroll
    for (int i = 0; i < 8; i++) Vt[(sd + i) * 40 + vcol] = (u16)vv[i];
    __syncthreads();

    // S^T = K @ Q^T : C row = kv = nb*16 + g*4 + r, col = q = fr
    f32x4 s[2];
    #pragma unroll
    for (int nb = 0; nb < 2; nb++) {
      short8 kf0 = *(const short8*)&Ks[(nb * 16 + fr) * 72 + g * 8];
      short8 kf1 = *(const short8*)&Ks[(nb * 16 + fr) * 72 + 32 + g * 8];
      f32x4 z = (f32x4){0.f, 0.f, 0.f, 0.f};
      z = MFMA_16x16x32(kf0, qf[0], z);
      z = MFMA_16x16x32(kf1, qf[1], z);
      s[nb] = z * 0.125f;  // 1/sqrt(64)
    }

    // online softmax for q=fr: in-register reduce over lane's 8 kv + 2 shfl across g
    float mx = s[0][0];
    #pragma unroll
    for (int nb = 0; nb < 2; nb++)
      #pragma unroll
      for (int r = 0; r < 4; r++) mx = fmaxf(mx, s[nb][r]);
    mx = fmaxf(mx, __shfl_xor(mx, 16));
    mx = fmaxf(mx, __shfl_xor(mx, 32));
    const float mnew = fmaxf(m_l, mx);
    const float corr = __expf(m_l - mnew);
    m_l = mnew;
    float ps = 0.f;
    #pragma unroll
    for (int nb = 0; nb < 2; nb++)
      #pragma unroll
      for (int r = 0; r < 4; r++) {
        float e = __expf(s[nb][r] - mnew);
        s[nb][r] = e;
        ps += e;
      }
    ps += __shfl_xor(ps, 16);
    ps += __shfl_xor(ps, 32);
    l_l = l_l * corr + ps;

    // rescale O (O rows: q = g*4 + r) — fetch corr for those q from the fr-holders
    float corr_t[4];
    #pragma unroll
    for (int r = 0; r < 4; r++) corr_t[r] = __shfl(corr, (lane & 48) | (g * 4 + r));
    #pragma unroll
    for (int db = 0; db < 4; db++)
      #pragma unroll
      for (int r = 0; r < 4; r++) o[db][r] *= corr_t[r];

    // pack P^T -> P in per-wave LDS: lane writes row q=fr, kv = nb*16 + g*4 + 0..3
    #pragma unroll
    for (int nb = 0; nb < 2; nb++) {
      short4v pk;
      #pragma unroll
      for (int r = 0; r < 4; r++) pk[r] = (short)f2bf(s[nb][r]);
      *(short4v*)&Ps[wid][fr * 40 + nb * 16 + g * 4] = pk;
    }
    short8 pf = *(const short8*)&Ps[wid][fr * 40 + g * 8];

    // O += P @ V  (B-frag from rotated Vt; same as round 4)
    #pragma unroll
    for (int db = 0; db < 4; db++) {
      short8 vf = *(const short8*)&Vt[(db * 16 + fr) * 40 + 8 * ((g + 2 * db + (fr >> 3)) & 3)];
      o[db] = MFMA_16x16x32(pf, vf, o[db]);
    }
    __syncthreads();
  }

  // epilogue: l for O rows q = g*4+r fetched from fr-holders, divide, store
  float l_t[4];
  #pragma unroll
  for (int r = 0; r < 4; r++) l_t[r] = __shfl(l_l, (lane & 48) | (g * 4 + r));
  #pragma unroll
  for (int db = 0; db < 4; db++)
    #pragma unroll
    for (int r = 0; r < 4; r++) {
      float v = o[db][r] / l_t[r];
      int row = qt * 64 + wid * 16 + g * 4 + r;
      ctx[(size_t)(b * 2048 + row) * 1024 + h * 64 + db * 16 + fr] = f2bf(v);
    }
}

// ---------- residual + LayerNorm:  y = LN(2*res + add)*g + be ----------
__global__ __launch_bounds__(256, 4)
void ln_kernel(const float* __restrict__ res, const float* __restrict__ add,
               const float* __restrict__ g, const float* __restrict__ be,
               float* __restrict__ yout, u16* __restrict__ ybf) {
  const int row = blockIdx.x;
  const float* rp = res + (size_t)row * 1024;
  const float* ap = add + (size_t)row * 1024;
  const int c0 = threadIdx.x * 4;
  float4 rv = *(const float4*)&rp[c0];
  float4 av = *(const float4*)&ap[c0];
  float v[4] = {2.f * rv.x + av.x, 2.f * rv.y + av.y, 2.f * rv.z + av.z, 2.f * rv.w + av.w};
  float s = 0.f, sq = 0.f;
  #pragma unroll
  for (int i = 0; i < 4; i++) { s += v[i]; sq += v[i] * v[i]; }
  #pragma unroll
  for (int off = 32; off; off >>= 1) { s += __shfl_xor(s, off, 64); sq += __shfl_xor(sq, off, 64); }
  __shared__ float red[8];
  const int wid = threadIdx.x >> 6;
  if ((threadIdx.x & 63) == 0) { red[wid] = s; red[4 + wid] = sq; }
  __syncthreads();
  s  = red[0] + red[1] + red[2] + red[3];
  sq = red[4] + red[5] + red[6] + red[7];
  const float mu   = s * (1.f / 1024.f);
  const float var  = sq * (1.f / 1024.f) - mu * mu;
  const float rstd = rsqrtf(var + 1e-5f);
  #pragma unroll
  for (int i = 0; i < 4; i++) {
    const int c = c0 + i;
    float y = (v[i] - mu) * rstd * g[c] + be[c];
    yout[(size_t)row * 1024 + c] = y;
    if (ybf) ybf[(size_t)row * 1024 + c] = f2bf(y);
  }
}

// ---------- launch ----------
extern "C" void kernel_launch(void* const* d_in, const int* in_sizes, int n_in,
                              void* d_out, int out_size, void* d_ws, size_t ws_size,
                              hipStream_t stream) {
  const float* x   = (const float*)d_in[0];
  const float* Wq  = (const float*)d_in[1];
  const float* Wk  = (const float*)d_in[2];
  const float* Wv  = (const float*)d_in[3];
  const float* Wo  = (const float*)d_in[4];
  const float* W1  = (const float*)d_in[5];
  const float* b1  = (const float*)d_in[6];
  const float* W2  = (const float*)d_in[7];
  const float* b2  = (const float*)d_in[8];
  const float* g1  = (const float*)d_in[9];
  const float* be1 = (const float*)d_in[10];
  const float* g2  = (const float*)d_in[11];
  const float* be2 = (const float*)d_in[12];
  float* out = (float*)d_out;
  char* ws = (char*)d_ws;
  const size_t MB = 1024 * 1024;

  u16*   qkv   = (u16*)(ws + 0);
  float* y1    = (float*)(ws + 0);
  u16*   y1b   = (u16*)(ws + 16 * MB);
  u16*   hb    = (u16*)(ws + 24 * MB);
  u16*   xb    = (u16*)(ws + 24 * MB);
  u16*   WqkvT = (u16*)(ws + 32 * MB);
  u16*   WoT   = (u16*)(ws + 38 * MB);
  u16*   ctx   = (u16*)(ws + 40 * MB);
  float* attnf = (float*)(ws + 56 * MB);
  float* fff   = (float*)(ws + 56 * MB);
  u16*   W1T   = (u16*)(ws + 72 * MB);
  u16*   W2T   = (u16*)(ws + 72 * MB);

  cast_bf16_kernel<<<dim3(4096), dim3(256), 0, stream>>>(x, xb);
  transpose_cast_kernel<<<dim3(32, 32), dim3(256), 0, stream>>>(Wq, WqkvT, 1024, 1024);
  transpose_cast_kernel<<<dim3(32, 32), dim3(256), 0, stream>>>(Wk, WqkvT + 1024 * 1024, 1024, 1024);
  transpose_cast_kernel<<<dim3(32, 32), dim3(256), 0, stream>>>(Wv, WqkvT + 2 * 1024 * 1024, 1024, 1024);
  gemm128<0><<<dim3(24, 32), dim3(256), 0, stream>>>(xb, WqkvT, qkv, nullptr, 4096, 3072, 1024);
  attn_kernel<<<dim3(32, 32), dim3(256), 0, stream>>>(qkv, ctx);
  transpose_cast_kernel<<<dim3(32, 32), dim3(256), 0, stream>>>(Wo, WoT, 1024, 1024);
  gemm128<1><<<dim3(8, 32), dim3(256), 0, stream>>>(ctx, WoT, attnf, nullptr, 4096, 1024, 1024);
  ln_kernel<<<dim3(4096), dim3(256), 0, stream>>>(x, attnf, g1, be1, y1, y1b);
  transpose_cast_kernel<<<dim3(128, 32), dim3(256), 0, stream>>>(W1, W1T, 1024, 4096);
  gemm128<2><<<dim3(32, 32), dim3(256), 0, stream>>>(y1b, W1T, hb, b1, 4096, 4096, 1024);
  transpose_cast_kernel<<<dim3(32, 128), dim3(256), 0, stream>>>(W2, W2T, 4096, 1024);
  gemm128<3><<<dim3(8, 32), dim3(256), 0, stream>>>(hb, W2T, fff, b2, 4096, 1024, 4096);
  ln_kernel<<<dim3(4096), dim3(256), 0, stream>>>(y1, fff, g2, be2, out, nullptr);
}

// Round 8
// 505.690 us; speedup vs baseline: 1.2206x; 1.0086x over previous
//
#include <hip/hip_runtime.h>
#include <hip/hip_bf16.h>

typedef unsigned short u16;
typedef unsigned int   u32;
typedef __attribute__((ext_vector_type(8))) short  short8;
typedef __attribute__((ext_vector_type(4))) short  short4v;
typedef __attribute__((ext_vector_type(4))) float  f32x4;

// ---------- helpers ----------
static __device__ __forceinline__ u16 f2bf(float f) {
  u32 u = __builtin_bit_cast(u32, f);
  u = (u + 0x7fffu + ((u >> 16) & 1u)) >> 16;
  return (u16)u;
}

#define MFMA_16x16x32(A,B,C) __builtin_amdgcn_mfma_f32_16x16x32_bf16((A),(B),(C),0,0,0)

static __device__ __forceinline__ void gload_lds16(const u16* g, u16* lds) {
  __builtin_amdgcn_global_load_lds((const __attribute__((address_space(1))) u32*)g,
                                   (__attribute__((address_space(3))) u32*)lds, 16, 0, 0);
}

static __device__ __forceinline__ float mishf(float x) {
  float sp = fmaxf(x, 0.f) + log1pf(__expf(-fabsf(x)));
  return x * tanhf(sp);
}

// ---------- cast fp32 -> bf16 (vectorized) ----------
__global__ __launch_bounds__(256) void cast_bf16_kernel(const float* __restrict__ x,
                                                        u16* __restrict__ o) {
  int i = (blockIdx.x * 256 + threadIdx.x) * 4;
  float4 v = *(const float4*)&x[i];
  short4v s;
  s[0] = (short)f2bf(v.x); s[1] = (short)f2bf(v.y);
  s[2] = (short)f2bf(v.z); s[3] = (short)f2bf(v.w);
  *(short4v*)&o[i] = s;
}

// ---------- transpose + cast: W[K][N] fp32 -> Out[N][K] bf16 ----------
__global__ __launch_bounds__(256) void transpose_cast_kernel(const float* __restrict__ W,
                                                             u16* __restrict__ Out,
                                                             int K, int N) {
  __shared__ float tile[32][33];
  const int k0 = blockIdx.y * 32, n0 = blockIdx.x * 32;
  const int tx = threadIdx.x & 31, ty = threadIdx.x >> 5;  // 32 x 8
  #pragma unroll
  for (int i = 0; i < 32; i += 8)
    tile[ty + i][tx] = W[(size_t)(k0 + ty + i) * N + n0 + tx];
  __syncthreads();
  #pragma unroll
  for (int i = 0; i < 32; i += 8)
    Out[(size_t)(n0 + ty + i) * K + k0 + tx] = f2bf(tile[tx][ty + i]);
}

// ---------- GEMM: C[M][N] = A[M][K](bf16) @ Bt[N][K](bf16)^T ----------
// EPI: 0 = store bf16, 1 = store fp32, 2 = +bias, mish, store bf16, 3 = +bias store fp32
template<int EPI>
__global__ __launch_bounds__(256, 2)
void gemm128(const u16* __restrict__ A, const u16* __restrict__ Bt,
             void* __restrict__ Cv, const float* __restrict__ bias,
             int M, int N, int K) {
  __shared__ __align__(16) u16 As[128 * 32];
  __shared__ __align__(16) u16 Bs[128 * 32];
  const int tid  = threadIdx.x;
  const int lane = tid & 63;
  const int wid  = tid >> 6;

  // XCD-aware swizzle (bijective: all grids here have nwg % 8 == 0)
  const u32 nwg = gridDim.x * gridDim.y;
  const u32 id  = blockIdx.y * gridDim.x + blockIdx.x;
  const u32 cpx = nwg >> 3;
  const u32 swz = (id & 7) * cpx + (id >> 3);
  const int bm = (swz / gridDim.x) * 128;
  const int bn = (swz % gridDim.x) * 128;

  const int wr = (wid >> 1) * 64;
  const int wc = (wid & 1) * 64;

  f32x4 acc[4][4];
  #pragma unroll
  for (int i = 0; i < 4; i++)
    #pragma unroll
    for (int j = 0; j < 4; j++) acc[i][j] = (f32x4){0.f, 0.f, 0.f, 0.f};

  const int srow = wid * 16 + (lane >> 2);
  const int scol = (lane & 3) * 8;
  const u16* Ag0 = A  + (size_t)(bm + srow) * K + scol;
  const u16* Ag1 = A  + (size_t)(bm + 64 + srow) * K + scol;
  const u16* Bg0 = Bt + (size_t)(bn + srow) * K + scol;
  const u16* Bg1 = Bt + (size_t)(bn + 64 + srow) * K + scol;
  u16* As0 = &As[wid * 512];
  u16* As1 = &As[2048 + wid * 512];
  u16* Bs0 = &Bs[wid * 512];
  u16* Bs1 = &Bs[2048 + wid * 512];

  const int fr = lane & 15;
  const int fk = (lane >> 4) * 8;

  for (int k0 = 0; k0 < K; k0 += 32) {
    gload_lds16(Ag0 + k0, As0);
    gload_lds16(Ag1 + k0, As1);
    gload_lds16(Bg0 + k0, Bs0);
    gload_lds16(Bg1 + k0, Bs1);
    __syncthreads();
    short8 af[4], bf[4];
    #pragma unroll
    for (int i = 0; i < 4; i++) af[i] = *(const short8*)&As[(wr + i * 16 + fr) * 32 + fk];
    #pragma unroll
    for (int j = 0; j < 4; j++) bf[j] = *(const short8*)&Bs[(wc + j * 16 + fr) * 32 + fk];
    #pragma unroll
    for (int i = 0; i < 4; i++)
      #pragma unroll
      for (int j = 0; j < 4; j++)
        acc[i][j] = MFMA_16x16x32(af[i], bf[j], acc[i][j]);
    __syncthreads();
  }

  const int r0 = (lane >> 4) * 4;
  #pragma unroll
  for (int i = 0; i < 4; i++) {
    const int row = bm + wr + i * 16 + r0;
    #pragma unroll
    for (int j = 0; j < 4; j++) {
      const int col = bn + wc + j * 16 + fr;
      float bv = 0.f;
      if (EPI >= 2) bv = bias[col];
      #pragma unroll
      for (int r = 0; r < 4; r++) {
        float v = acc[i][j][r] + bv;
        if (EPI == 2) v = mishf(v);
        if (EPI == 0 || EPI == 2)
          ((u16*)Cv)[(size_t)(row + r) * N + col] = f2bf(v);
        else
          ((float*)Cv)[(size_t)(row + r) * N + col] = v;
      }
    }
  }
}

// ---------- flash attention (r5 structure; V^T writes kv-pair-packed as u32) ----------
// qkv: [B*T][3072] bf16, cols = which*1024 + h*64 + d.  ctx out: [B*T][1024] bf16.
// grid: (32 q-tiles of 64 rows, 32 bh). block 256 = 4 waves; wave handles 16 q rows.
__global__ __launch_bounds__(256, 2)
void attn_kernel(const u16* __restrict__ qkv, u16* __restrict__ ctx) {
  const int bh = blockIdx.y;
  const int b = bh >> 4, h = bh & 15;
  const int qt = blockIdx.x;
  const int tid = threadIdx.x, lane = tid & 63, wid = tid >> 6;

  __shared__ __align__(16) u16 Ks[32 * 72];      // [kt][d], padded to 72
  __shared__ __align__(16) u16 Vt[64 * 40];      // [d][kt rotated by 8*(d>>3) mod 32], pad 40
  __shared__ __align__(16) u16 Ps[4][16 * 40];   // per-wave P tile [q][kv], rows of 40

  const size_t base = (size_t)b * 2048 * 3072;
  const int fr = lane & 15;
  const int g  = lane >> 4;   // 16-lane group

  // Q fragment: q = fr, k = d = g*8+i. Serves as B-frag of swapped QK^T.
  short8 qf[2];
  {
    const int qrow = qt * 64 + wid * 16 + fr;
    const u16* qp = qkv + base + (size_t)qrow * 3072 + h * 64 + g * 8;
    qf[0] = *(const short8*)qp;
    qf[1] = *(const short8*)(qp + 32);
  }

  float m_l = -1e30f, l_l = 0.f;   // running stats for q-row = fr
  f32x4 o[4];
  #pragma unroll
  for (int d = 0; d < 4; d++) o[d] = (f32x4){0.f, 0.f, 0.f, 0.f};

  const int srow = tid >> 3;         // K staging: kv row 0..31
  const int sd   = (tid & 7) * 8;    // K staging: d offset
  const int vu   = tid >> 4;         // V staging: kv-pair index 0..15
  const int vdg  = tid & 15;         // V staging: d-group (4 cols)

  for (int kt = 0; kt < 2048; kt += 32) {
    // stage K row-major (padded)
    const u16* kp = qkv + base + (size_t)(kt + srow) * 3072 + 1024 + h * 64 + sd;
    short8 kv = *(const short8*)kp;
    // stage V transposed: kv-pair (2u,2u+1) packed into one u32 per d.
    // col(kv) = (kv + 8*(d>>3)) & 31  — identical mapping to r5's write/read pair.
    const u16* vp = qkv + base + (size_t)(kt + 2 * vu) * 3072 + 2048 + h * 64 + vdg * 4;
    short4v v0 = *(const short4v*)vp;
    short4v v1 = *(const short4v*)(vp + 3072);
    *(short8*)&Ks[srow * 72 + sd] = kv;
    #pragma unroll
    for (int i = 0; i < 4; i++) {
      const int d = vdg * 4 + i;
      const int vcol = (2 * vu + 8 * ((d >> 3) & 3)) & 31;
      *(u32*)&Vt[d * 40 + vcol] = ((u32)(u16)v0[i]) | ((u32)(u16)v1[i] << 16);
    }
    __syncthreads();

    // S^T = K @ Q^T : C row = kv = nb*16 + g*4 + r, col = q = fr
    f32x4 s[2];
    #pragma unroll
    for (int nb = 0; nb < 2; nb++) {
      short8 kf0 = *(const short8*)&Ks[(nb * 16 + fr) * 72 + g * 8];
      short8 kf1 = *(const short8*)&Ks[(nb * 16 + fr) * 72 + 32 + g * 8];
      f32x4 z = (f32x4){0.f, 0.f, 0.f, 0.f};
      z = MFMA_16x16x32(kf0, qf[0], z);
      z = MFMA_16x16x32(kf1, qf[1], z);
      s[nb] = z * 0.125f;  // 1/sqrt(64)
    }

    // online softmax for q=fr: in-register reduce over lane's 8 kv + 2 shfl across g
    float mx = s[0][0];
    #pragma unroll
    for (int nb = 0; nb < 2; nb++)
      #pragma unroll
      for (int r = 0; r < 4; r++) mx = fmaxf(mx, s[nb][r]);
    mx = fmaxf(mx, __shfl_xor(mx, 16));
    mx = fmaxf(mx, __shfl_xor(mx, 32));
    const float mnew = fmaxf(m_l, mx);
    const float corr = __expf(m_l - mnew);
    m_l = mnew;
    float ps = 0.f;
    #pragma unroll
    for (int nb = 0; nb < 2; nb++)
      #pragma unroll
      for (int r = 0; r < 4; r++) {
        float e = __expf(s[nb][r] - mnew);
        s[nb][r] = e;
        ps += e;
      }
    ps += __shfl_xor(ps, 16);
    ps += __shfl_xor(ps, 32);
    l_l = l_l * corr + ps;

    // rescale O (O rows: q = g*4 + r)
    float corr_t[4];
    #pragma unroll
    for (int r = 0; r < 4; r++) corr_t[r] = __shfl(corr, (lane & 48) | (g * 4 + r));
    #pragma unroll
    for (int db = 0; db < 4; db++)
      #pragma unroll
      for (int r = 0; r < 4; r++) o[db][r] *= corr_t[r];

    // pack P^T -> P in per-wave LDS: lane writes row q=fr, kv = nb*16 + g*4 + 0..3
    #pragma unroll
    for (int nb = 0; nb < 2; nb++) {
      short4v pk;
      #pragma unroll
      for (int r = 0; r < 4; r++) pk[r] = (short)f2bf(s[nb][r]);
      *(short4v*)&Ps[wid][fr * 40 + nb * 16 + g * 4] = pk;
    }
    short8 pf = *(const short8*)&Ps[wid][fr * 40 + g * 8];

    // O += P @ V  (B-frag from rotated Vt; identical to r5)
    #pragma unroll
    for (int db = 0; db < 4; db++) {
      short8 vf = *(const short8*)&Vt[(db * 16 + fr) * 40 + 8 * ((g + 2 * db + (fr >> 3)) & 3)];
      o[db] = MFMA_16x16x32(pf, vf, o[db]);
    }
    __syncthreads();
  }

  // epilogue: l for O rows q = g*4+r fetched from fr-holders, divide, store
  float l_t[4];
  #pragma unroll
  for (int r = 0; r < 4; r++) l_t[r] = __shfl(l_l, (lane & 48) | (g * 4 + r));
  #pragma unroll
  for (int db = 0; db < 4; db++)
    #pragma unroll
    for (int r = 0; r < 4; r++) {
      float v = o[db][r] / l_t[r];
      int row = qt * 64 + wid * 16 + g * 4 + r;
      ctx[(size_t)(b * 2048 + row) * 1024 + h * 64 + db * 16 + fr] = f2bf(v);
    }
}

// ---------- residual + LayerNorm:  y = LN(2*res + add)*g + be ----------
__global__ __launch_bounds__(256, 4)
void ln_kernel(const float* __restrict__ res, const float* __restrict__ add,
               const float* __restrict__ g, const float* __restrict__ be,
               float* __restrict__ yout, u16* __restrict__ ybf) {
  const int row = blockIdx.x;
  const float* rp = res + (size_t)row * 1024;
  const float* ap = add + (size_t)row * 1024;
  const int c0 = threadIdx.x * 4;
  float4 rv = *(const float4*)&rp[c0];
  float4 av = *(const float4*)&ap[c0];
  float v[4] = {2.f * rv.x + av.x, 2.f * rv.y + av.y, 2.f * rv.z + av.z, 2.f * rv.w + av.w};
  float s = 0.f, sq = 0.f;
  #pragma unroll
  for (int i = 0; i < 4; i++) { s += v[i]; sq += v[i] * v[i]; }
  #pragma unroll
  for (int off = 32; off; off >>= 1) { s += __shfl_xor(s, off, 64); sq += __shfl_xor(sq, off, 64); }
  __shared__ float red[8];
  const int wid = threadIdx.x >> 6;
  if ((threadIdx.x & 63) == 0) { red[wid] = s; red[4 + wid] = sq; }
  __syncthreads();
  s  = red[0] + red[1] + red[2] + red[3];
  sq = red[4] + red[5] + red[6] + red[7];
  const float mu   = s * (1.f / 1024.f);
  const float var  = sq * (1.f / 1024.f) - mu * mu;
  const float rstd = rsqrtf(var + 1e-5f);
  #pragma unroll
  for (int i = 0; i < 4; i++) {
    const int c = c0 + i;
    float y = (v[i] - mu) * rstd * g[c] + be[c];
    yout[(size_t)row * 1024 + c] = y;
    if (ybf) ybf[(size_t)row * 1024 + c] = f2bf(y);
  }
}

// ---------- launch ----------
extern "C" void kernel_launch(void* const* d_in, const int* in_sizes, int n_in,
                              void* d_out, int out_size, void* d_ws, size_t ws_size,
                              hipStream_t stream) {
  const float* x   = (const float*)d_in[0];
  const float* Wq  = (const float*)d_in[1];
  const float* Wk  = (const float*)d_in[2];
  const float* Wv  = (const float*)d_in[3];
  const float* Wo  = (const float*)d_in[4];
  const float* W1  = (const float*)d_in[5];
  const float* b1  = (const float*)d_in[6];
  const float* W2  = (const float*)d_in[7];
  const float* b2  = (const float*)d_in[8];
  const float* g1  = (const float*)d_in[9];
  const float* be1 = (const float*)d_in[10];
  const float* g2  = (const float*)d_in[11];
  const float* be2 = (const float*)d_in[12];
  float* out = (float*)d_out;
  char* ws = (char*)d_ws;
  const size_t MB = 1024 * 1024;

  u16*   qkv   = (u16*)(ws + 0);
  float* y1    = (float*)(ws + 0);
  u16*   y1b   = (u16*)(ws + 16 * MB);
  u16*   hb    = (u16*)(ws + 24 * MB);
  u16*   xb    = (u16*)(ws + 24 * MB);
  u16*   WqkvT = (u16*)(ws + 32 * MB);
  u16*   WoT   = (u16*)(ws + 38 * MB);
  u16*   ctx   = (u16*)(ws + 40 * MB);
  float* attnf = (float*)(ws + 56 * MB);
  float* fff   = (float*)(ws + 56 * MB);
  u16*   W1T   = (u16*)(ws + 72 * MB);
  u16*   W2T   = (u16*)(ws + 72 * MB);

  cast_bf16_kernel<<<dim3(4096), dim3(256), 0, stream>>>(x, xb);
  transpose_cast_kernel<<<dim3(32, 32), dim3(256), 0, stream>>>(Wq, WqkvT, 1024, 1024);
  transpose_cast_kernel<<<dim3(32, 32), dim3(256), 0, stream>>>(Wk, WqkvT + 1024 * 1024, 1024, 1024);
  transpose_cast_kernel<<<dim3(32, 32), dim3(256), 0, stream>>>(Wv, WqkvT + 2 * 1024 * 1024, 1024, 1024);
  gemm128<0><<<dim3(24, 32), dim3(256), 0, stream>>>(xb, WqkvT, qkv, nullptr, 4096, 3072, 1024);
  attn_kernel<<<dim3(32, 32), dim3(256), 0, stream>>>(qkv, ctx);
  transpose_cast_kernel<<<dim3(32, 32), dim3(256), 0, stream>>>(Wo, WoT, 1024, 1024);
  gemm128<1><<<dim3(8, 32), dim3(256), 0, stream>>>(ctx, WoT, attnf, nullptr, 4096, 1024, 1024);
  ln_kernel<<<dim3(4096), dim3(256), 0, stream>>>(x, attnf, g1, be1, y1, y1b);
  transpose_cast_kernel<<<dim3(128, 32), dim3(256), 0, stream>>>(W1, W1T, 1024, 4096);
  gemm128<2><<<dim3(32, 32), dim3(256), 0, stream>>>(y1b, W1T, hb, b1, 4096, 4096, 1024);
  transpose_cast_kernel<<<dim3(32, 128), dim3(256), 0, stream>>>(W2, W2T, 4096, 1024);
  gemm128<3><<<dim3(8, 32), dim3(256), 0, stream>>>(hb, W2T, fff, b2, 4096, 1024, 4096);
  ln_kernel<<<dim3(4096), dim3(256), 0, stream>>>(y1, fff, g2, be2, out, nullptr);
}